// Round 1
// baseline (492.861 us; speedup 1.0000x reference)
//
#include <hip/hip_runtime.h>
#include <stdint.h>

#define EPSV 1e-5f

typedef __attribute__((ext_vector_type(8))) short short8;
typedef __attribute__((ext_vector_type(4))) float f32x4;
typedef __bf16 bf16x8 __attribute__((ext_vector_type(8)));

__device__ __forceinline__ unsigned short f2bf(float f) {
  union { float f; unsigned int u; } v; v.f = f;
  unsigned int r = (v.u + 0x7FFFu + ((v.u >> 16) & 1u)) >> 16;
  return (unsigned short)r;
}
__device__ __forceinline__ float bf2f(unsigned short h) {
  union { unsigned int u; float f; } v; v.u = ((unsigned int)h) << 16;
  return v.f;
}

__device__ __forceinline__ f32x4 mfma16(bf16x8 a, bf16x8 b, f32x4 c) {
  return __builtin_amdgcn_mfma_f32_16x16x32_bf16(a, b, c, 0, 0, 0);
}

#define GLOAD16(g, l)                                                          \
  __builtin_amdgcn_global_load_lds(                                            \
      (const __attribute__((address_space(1))) void*)(g),                      \
      (__attribute__((address_space(3))) void*)(l), 16, 0, 0)

// ---------------- GroupNorm stats: per-sample sum / sumsq ----------------
__global__ __launch_bounds__(256) void k_gn_stats(const float* __restrict__ x,
                                                  float* __restrict__ stats) {
  int b = blockIdx.x >> 6, chunk = blockIdx.x & 63;
  const float4* xp = (const float4*)(x + ((size_t)b << 20) + (size_t)chunk * 16384);
  int t = threadIdx.x;
  float s = 0.f, q = 0.f;
#pragma unroll
  for (int i = 0; i < 16; ++i) {
    float4 v = xp[i * 256 + t];
    s += v.x + v.y + v.z + v.w;
    q += v.x * v.x + v.y * v.y + v.z * v.z + v.w * v.w;
  }
#pragma unroll
  for (int m = 1; m <= 32; m <<= 1) { s += __shfl_xor(s, m); q += __shfl_xor(q, m); }
  __shared__ float ls[8];
  int w = t >> 6, l = t & 63;
  if (l == 0) { ls[w * 2] = s; ls[w * 2 + 1] = q; }
  __syncthreads();
  if (t == 0) {
    float S = ls[0] + ls[2] + ls[4] + ls[6];
    float Q = ls[1] + ls[3] + ls[5] + ls[7];
    atomicAdd(&stats[b * 2], S);
    atomicAdd(&stats[b * 2 + 1], Q);
  }
}

// ---------- normalize + NCHW->padded-NHWC transpose (bf16) ----------
__global__ __launch_bounds__(256) void k_gn_norm(const float* __restrict__ x,
                                                 const float* __restrict__ stats,
                                                 const float* __restrict__ g,
                                                 const float* __restrict__ bb,
                                                 unsigned short* __restrict__ xnp) {
  __shared__ float tile[64][65];
  int pt = blockIdx.x;  // image row y (64 pixels)
  int ct = blockIdx.y;  // ci tile (4)
  int b = blockIdx.z;
  int t = threadIdx.x, tr = t >> 6, tc = t & 63;
  const float* xb = x + ((size_t)b << 20) + (size_t)(ct * 64) * 4096 + pt * 64;
#pragma unroll
  for (int i = 0; i < 16; ++i) {
    int r = i * 4 + tr;
    tile[r][tc] = xb[(size_t)r * 4096 + tc];
  }
  __syncthreads();
  float mu = stats[b * 2] * (1.f / 1048576.f);
  float var = stats[b * 2 + 1] * (1.f / 1048576.f) - mu * mu;
  float istd = rsqrtf(var + EPSV);
  float gg = g[ct * 64 + tc] * istd;
  float bv = bb[ct * 64 + tc];
  unsigned short* out = xnp + (((size_t)b * 66 + (pt + 1)) * 66 + 1) * 256 + ct * 64 + tc;
#pragma unroll
  for (int i = 0; i < 16; ++i) {
    int pcol = i * 4 + tr;
    float v = (tile[tc][pcol] - mu) * gg + bv;
    out[(size_t)pcol * 256] = f2bf(v);
  }
}

// ------------- weight prep: w_in -> wt[tap][co][ci] bf16, BN folded -------------
__global__ __launch_bounds__(256) void k_prep_wt(const float* __restrict__ w_in,
                                                 const float* __restrict__ bg,
                                                 const float* __restrict__ bv,
                                                 unsigned short* __restrict__ wt) {
  int idx = blockIdx.x * 256 + threadIdx.x;
  if (idx >= 9 * 384 * 256) return;
  int tap = idx / 98304;
  int rem = idx - tap * 98304;
  int co = rem >> 8, ci = rem & 255;
  float s = bg[co] * rsqrtf(bv[co] + EPSV);
  wt[idx] = f2bf(w_in[(size_t)(co * 256 + ci) * 9 + tap] * s);
}

__global__ __launch_bounds__(256) void k_prep_misc(
    const float* w_out, const float* og, const float* ob, const float* om, const float* ov,
    const float* big, const float* bib, const float* bim, const float* biv,
    const float* w_k, const float* kg, const float* kb, const float* km, const float* kvv,
    const float* w_v, const float* vg, const float* vb, const float* vm, const float* vvv,
    unsigned short* wo2, float* bias_in, float* bias_out,
    float* wkf, float* bias_k, float* wvf, float* bias_v) {
  int idx = blockIdx.x * 256 + threadIdx.x;
  if (idx < 65536) {
    int co = idx >> 8;
    float s = og[co] * rsqrtf(ov[co] + EPSV);
    wo2[idx] = f2bf(w_out[idx] * s);
    return;
  }
  idx -= 65536;
  if (idx < 384) {
    float s = big[idx] * rsqrtf(biv[idx] + EPSV);
    bias_in[idx] = bib[idx] - bim[idx] * s;
    return;
  }
  idx -= 384;
  if (idx < 256) {
    float s = og[idx] * rsqrtf(ov[idx] + EPSV);
    bias_out[idx] = ob[idx] - om[idx] * s;
    return;
  }
  idx -= 256;
  if (idx < 64) {
    float s = kg[idx] * rsqrtf(kvv[idx] + EPSV);
#pragma unroll
    for (int tp = 0; tp < 4; ++tp) wkf[idx * 4 + tp] = w_k[idx * 4 + tp] * s;
    bias_k[idx] = kb[idx] - km[idx] * s;
    return;
  }
  idx -= 64;
  if (idx < 128) {
    float s = vg[idx] * rsqrtf(vvv[idx] + EPSV);
#pragma unroll
    for (int tp = 0; tp < 4; ++tp) wvf[idx * 4 + tp] = w_v[idx * 4 + tp] * s;
    bias_v[idx] = vb[idx] - vm[idx] * s;
    return;
  }
}

// ---------------- conv3x3 implicit GEMM: y[b][p][co] bf16 ----------------
// D[p][co], per-batch M=4096,N=384,K=9*256. Tile 128x128, 4 waves 2x2.
__global__ __launch_bounds__(256) void k_conv3(const unsigned short* __restrict__ xnp,
                                               const unsigned short* __restrict__ wt,
                                               const float* __restrict__ bias_in,
                                               unsigned short* __restrict__ y) {
  int pt = blockIdx.x, cot = blockIdx.y, b = blockIdx.z;
  int p0 = pt * 128, co0 = cot * 128;
  __shared__ alignas(16) unsigned short As[128 * 64];
  __shared__ alignas(16) unsigned short Bs[128 * 64];
  int t = threadIdx.x, w = t >> 6, l = t & 63;
  int rr = t >> 3, c8 = (t & 7) * 8;
  int lg = l >> 4, lr = l & 15;

  int baseA[4];
#pragma unroll
  for (int i = 0; i < 4; ++i) {
    int p = p0 + i * 32 + rr;
    int yy = p >> 6, xx = p & 63;
    baseA[i] = ((b * 66 + yy) * 66 + xx) * 256 + c8;
  }
  int baseB = (co0 + rr) * 256 + c8;

  f32x4 acc[4][4];
#pragma unroll
  for (int i = 0; i < 4; ++i)
#pragma unroll
    for (int j = 0; j < 4; ++j) acc[i][j] = f32x4{0.f, 0.f, 0.f, 0.f};

  int wr = (w >> 1) * 64, wc = (w & 1) * 64;

  for (int tap = 0; tap < 9; ++tap) {
    int aoff = ((tap / 3) * 66 + (tap % 3)) * 256;
#pragma unroll 1
    for (int kc = 0; kc < 4; ++kc) {
      int ci0 = kc * 64;
      __syncthreads();
#pragma unroll
      for (int i = 0; i < 4; ++i) {
        GLOAD16(xnp + baseA[i] + aoff + ci0, &As[(i * 32 + w * 8) * 64]);
        GLOAD16(wt + baseB + tap * 98304 + i * 8192 + ci0, &Bs[(i * 32 + w * 8) * 64]);
      }
      __syncthreads();
      bf16x8 af[4][2], bf[4][2];
#pragma unroll
      for (int mt = 0; mt < 4; ++mt)
#pragma unroll
        for (int k2 = 0; k2 < 2; ++k2) {
          af[mt][k2] = *(const bf16x8*)&As[(wr + mt * 16 + lr) * 64 + k2 * 32 + lg * 8];
          bf[mt][k2] = *(const bf16x8*)&Bs[(wc + mt * 16 + lr) * 64 + k2 * 32 + lg * 8];
        }
#pragma unroll
      for (int mt = 0; mt < 4; ++mt)
#pragma unroll
        for (int nt = 0; nt < 4; ++nt) {
          acc[mt][nt] = mfma16(af[mt][0], bf[nt][0], acc[mt][nt]);
          acc[mt][nt] = mfma16(af[mt][1], bf[nt][1], acc[mt][nt]);
        }
    }
  }
  float bias[4];
  int coBase = co0 + wc;
#pragma unroll
  for (int nt = 0; nt < 4; ++nt) bias[nt] = bias_in[coBase + nt * 16 + lr];
#pragma unroll
  for (int mt = 0; mt < 4; ++mt) {
    int p = p0 + wr + mt * 16 + lg * 4;
#pragma unroll
    for (int r = 0; r < 4; ++r) {
      size_t rowoff = ((size_t)(b * 4096 + p + r)) * 384;
#pragma unroll
      for (int nt = 0; nt < 4; ++nt) {
        int co = coBase + nt * 16 + lr;
        float v = acc[mt][nt][r] + bias[nt];
        if (co >= 256) v = fmaxf(v, 0.f);  // pre-ReLU the u channels
        y[rowoff + co] = f2bf(v);
      }
    }
  }
}

// ------------- depthwise 2x2 stride-2 convs: kk[b][m][c], vv[b][cv][m] -------------
__global__ __launch_bounds__(256) void k_kv(const unsigned short* __restrict__ y,
                                            const float* __restrict__ wkf, const float* __restrict__ bias_k,
                                            const float* __restrict__ wvf, const float* __restrict__ bias_v,
                                            unsigned short* __restrict__ kk, unsigned short* __restrict__ vv) {
  int idx = blockIdx.x * 256 + threadIdx.x;
  if (idx < 16 * 1024 * 64) {
    int c = idx & 63, m = (idx >> 6) & 1023, b = idx >> 16;
    int my = m >> 5, mx = m & 31;
    float acc = bias_k[c];
#pragma unroll
    for (int tp = 0; tp < 4; ++tp) {
      int dy = tp >> 1, dx = tp & 1;
      int p = (2 * my + dy) * 64 + 2 * mx + dx;
      acc += bf2f(y[((size_t)(b * 4096 + p)) * 384 + 64 + c]) * wkf[c * 4 + tp];
    }
    kk[idx] = f2bf(acc);
  } else {
    int i2 = idx - 16 * 1024 * 64;
    if (i2 >= 16 * 128 * 1024) return;
    int m = i2 & 1023, cv = (i2 >> 10) & 127, b = i2 >> 17;
    int my = m >> 5, mx = m & 31;
    float acc = bias_v[cv];
#pragma unroll
    for (int tp = 0; tp < 4; ++tp) {
      int dy = tp >> 1, dx = tp & 1;
      int p = (2 * my + dy) * 64 + 2 * mx + dx;
      acc += bf2f(y[((size_t)(b * 4096 + p)) * 384 + 128 + cv]) * wvf[cv * 4 + tp];
    }
    vv[i2] = f2bf(acc);
  }
}

// ---------------- flash attention; writes relu(o) into y channels 128..255 ----------------
__global__ __launch_bounds__(256) void k_attn(unsigned short* __restrict__ y,
                                              const unsigned short* __restrict__ kk,
                                              const unsigned short* __restrict__ vvb) {
  int blk = blockIdx.x;
  int b = blk >> 5, ntile = blk & 31;
  int t = threadIdx.x, w = t >> 6, l = t & 63;
  int nq0 = ntile * 128 + w * 32;
  int lg = l >> 4, lr = l & 15;
  __shared__ alignas(16) unsigned short P[4][2][16][64];
  const float SC = 0.125f * 1.44269504f;  // scale * log2(e)

  bf16x8 qf[2][2];
#pragma unroll
  for (int qt = 0; qt < 2; ++qt)
#pragma unroll
    for (int c = 0; c < 2; ++c)
      qf[qt][c] = *(const bf16x8*)&y[((size_t)(b * 4096 + nq0 + qt * 16 + lr)) * 384 + c * 32 + lg * 8];

  f32x4 oa[2][8];
#pragma unroll
  for (int qt = 0; qt < 2; ++qt)
#pragma unroll
    for (int tt = 0; tt < 8; ++tt) oa[qt][tt] = f32x4{0.f, 0.f, 0.f, 0.f};
  float mi[2][4], li[2][4];
#pragma unroll
  for (int qt = 0; qt < 2; ++qt)
#pragma unroll
    for (int r = 0; r < 4; ++r) { mi[qt][r] = -1e30f; li[qt][r] = 0.f; }

  for (int m0 = 0; m0 < 1024; m0 += 64) {
    bf16x8 kf[4][2];
#pragma unroll
    for (int mt = 0; mt < 4; ++mt)
#pragma unroll
      for (int c = 0; c < 2; ++c)
        kf[mt][c] = *(const bf16x8*)&kk[((size_t)(b * 1024 + m0 + mt * 16 + lr)) * 64 + c * 32 + lg * 8];

#pragma unroll
    for (int qt = 0; qt < 2; ++qt) {
      f32x4 s[4];
#pragma unroll
      for (int mt = 0; mt < 4; ++mt) {
        f32x4 z = f32x4{0.f, 0.f, 0.f, 0.f};
        z = mfma16(qf[qt][0], kf[mt][0], z);
        z = mfma16(qf[qt][1], kf[mt][1], z);
        s[mt] = z;
      }
#pragma unroll
      for (int mt = 0; mt < 4; ++mt)
#pragma unroll
        for (int r = 0; r < 4; ++r) s[mt][r] *= SC;
      float rm[4];
#pragma unroll
      for (int r = 0; r < 4; ++r)
        rm[r] = fmaxf(fmaxf(s[0][r], s[1][r]), fmaxf(s[2][r], s[3][r]));
#pragma unroll
      for (int msk = 1; msk <= 8; msk <<= 1)
#pragma unroll
        for (int r = 0; r < 4; ++r) rm[r] = fmaxf(rm[r], __shfl_xor(rm[r], msk));
      float corr[4], rs[4];
#pragma unroll
      for (int r = 0; r < 4; ++r) {
        float nm = fmaxf(mi[qt][r], rm[r]);
        corr[r] = exp2f(mi[qt][r] - nm);
        mi[qt][r] = nm;
#pragma unroll
        for (int mt = 0; mt < 4; ++mt) s[mt][r] = exp2f(s[mt][r] - nm);
        rs[r] = s[0][r] + s[1][r] + s[2][r] + s[3][r];
      }
#pragma unroll
      for (int msk = 1; msk <= 8; msk <<= 1)
#pragma unroll
        for (int r = 0; r < 4; ++r) rs[r] += __shfl_xor(rs[r], msk);
#pragma unroll
      for (int r = 0; r < 4; ++r) li[qt][r] = li[qt][r] * corr[r] + rs[r];
#pragma unroll
      for (int tt = 0; tt < 8; ++tt)
#pragma unroll
        for (int r = 0; r < 4; ++r) oa[qt][tt][r] *= corr[r];
#pragma unroll
      for (int mt = 0; mt < 4; ++mt)
#pragma unroll
        for (int r = 0; r < 4; ++r)
          P[w][qt][lg * 4 + r][mt * 16 + lr] = f2bf(s[mt][r]);
    }
    __builtin_amdgcn_wave_barrier();
    bf16x8 pf[2][2];
#pragma unroll
    for (int qt = 0; qt < 2; ++qt)
#pragma unroll
      for (int mc = 0; mc < 2; ++mc)
        pf[qt][mc] = *(const bf16x8*)&P[w][qt][lr][mc * 32 + lg * 8];
#pragma unroll
    for (int tt = 0; tt < 8; ++tt) {
      bf16x8 vf0 = *(const bf16x8*)&vvb[((size_t)(b * 128 + tt * 16 + lr)) * 1024 + m0 + lg * 8];
      bf16x8 vf1 = *(const bf16x8*)&vvb[((size_t)(b * 128 + tt * 16 + lr)) * 1024 + m0 + 32 + lg * 8];
#pragma unroll
      for (int qt = 0; qt < 2; ++qt) {
        oa[qt][tt] = mfma16(pf[qt][0], vf0, oa[qt][tt]);
        oa[qt][tt] = mfma16(pf[qt][1], vf1, oa[qt][tt]);
      }
    }
  }
#pragma unroll
  for (int qt = 0; qt < 2; ++qt)
#pragma unroll
    for (int r = 0; r < 4; ++r) {
      float inv = 1.f / li[qt][r];
      int p = nq0 + qt * 16 + lg * 4 + r;
#pragma unroll
      for (int tt = 0; tt < 8; ++tt) {
        float v = oa[qt][tt][r] * inv;
        v = fmaxf(v, 0.f);  // pre-ReLU for conv1x1
        y[((size_t)(b * 4096 + p)) * 384 + 128 + tt * 16 + lr] = f2bf(v);
      }
    }
}

// ---------------- conv1x1 GEMM: out[b][co][p] f32 (NCHW) ----------------
// D[co][p] = sum_ci w2[co][ci] * relu_cat[p][ci];  relu_cat = y[.][128+ci]
__global__ __launch_bounds__(256) void k_conv1(const unsigned short* __restrict__ y,
                                               const unsigned short* __restrict__ wo2,
                                               const float* __restrict__ bias_out,
                                               float* __restrict__ out) {
  int ptile = blockIdx.x, cot = blockIdx.y, b = blockIdx.z;
  int p0 = ptile * 128, co0 = cot * 128;
  __shared__ alignas(16) unsigned short As[128 * 64];
  __shared__ alignas(16) unsigned short Bs[128 * 64];
  int t = threadIdx.x, w = t >> 6, l = t & 63;
  int rr = t >> 3, c8 = (t & 7) * 8;
  int lg = l >> 4, lr = l & 15;
  int baseA = (co0 + rr) * 256 + c8;
  size_t baseB = ((size_t)(b * 4096 + p0 + rr)) * 384 + 128 + c8;
  f32x4 acc[4][4];
#pragma unroll
  for (int i = 0; i < 4; ++i)
#pragma unroll
    for (int j = 0; j < 4; ++j) acc[i][j] = f32x4{0.f, 0.f, 0.f, 0.f};
  int wr = (w >> 1) * 64, wc = (w & 1) * 64;  // wr: co half, wc: p half
#pragma unroll 1
  for (int kc = 0; kc < 4; ++kc) {
    int ci0 = kc * 64;
    __syncthreads();
#pragma unroll
    for (int i = 0; i < 4; ++i) {
      GLOAD16(wo2 + baseA + i * 8192 + ci0, &As[(i * 32 + w * 8) * 64]);
      GLOAD16(y + baseB + (size_t)i * 32 * 384 + ci0, &Bs[(i * 32 + w * 8) * 64]);
    }
    __syncthreads();
    bf16x8 af[4][2], bf[4][2];
#pragma unroll
    for (int mt = 0; mt < 4; ++mt)
#pragma unroll
      for (int k2 = 0; k2 < 2; ++k2) {
        af[mt][k2] = *(const bf16x8*)&As[(wr + mt * 16 + lr) * 64 + k2 * 32 + lg * 8];
        bf[mt][k2] = *(const bf16x8*)&Bs[(wc + mt * 16 + lr) * 64 + k2 * 32 + lg * 8];
      }
#pragma unroll
    for (int mt = 0; mt < 4; ++mt)
#pragma unroll
      for (int nt = 0; nt < 4; ++nt) {
        acc[mt][nt] = mfma16(af[mt][0], bf[nt][0], acc[mt][nt]);
        acc[mt][nt] = mfma16(af[mt][1], bf[nt][1], acc[mt][nt]);
      }
  }
#pragma unroll
  for (int mt = 0; mt < 4; ++mt)
#pragma unroll
    for (int r = 0; r < 4; ++r) {
      int co = co0 + wr + mt * 16 + lg * 4 + r;
      float bv = bias_out[co];
      size_t obase = ((size_t)(b * 256 + co)) << 12;
#pragma unroll
      for (int nt = 0; nt < 4; ++nt) {
        int p = p0 + wc + nt * 16 + lr;
        out[obase + p] = acc[mt][nt][r] + bv;
      }
    }
}

// ---------------- host launch ----------------
static constexpr size_t pad256(size_t x) { return (x + 255) & ~(size_t)255; }

extern "C" void kernel_launch(void* const* d_in, const int* in_sizes, int n_in,
                              void* d_out, int out_size, void* d_ws, size_t ws_size,
                              hipStream_t stream) {
  const float* x      = (const float*)d_in[0];
  const float* gn_g   = (const float*)d_in[1];
  const float* gn_b   = (const float*)d_in[2];
  const float* w_in   = (const float*)d_in[3];
  const float* bin_g  = (const float*)d_in[4];
  const float* bin_b  = (const float*)d_in[5];
  const float* bin_m  = (const float*)d_in[6];
  const float* bin_v  = (const float*)d_in[7];
  const float* w_k    = (const float*)d_in[8];
  const float* bk_g   = (const float*)d_in[9];
  const float* bk_b   = (const float*)d_in[10];
  const float* bk_m   = (const float*)d_in[11];
  const float* bk_v   = (const float*)d_in[12];
  const float* w_v    = (const float*)d_in[13];
  const float* bv_g   = (const float*)d_in[14];
  const float* bv_b   = (const float*)d_in[15];
  const float* bv_m   = (const float*)d_in[16];
  const float* bv_v   = (const float*)d_in[17];
  const float* w_out  = (const float*)d_in[18];
  const float* bo_g   = (const float*)d_in[19];
  const float* bo_b   = (const float*)d_in[20];
  const float* bo_m   = (const float*)d_in[21];
  const float* bo_v   = (const float*)d_in[22];
  float* out = (float*)d_out;

  char* ws = (char*)d_ws;
  size_t off = 0;
  float*          stats   = (float*)(ws + off);          off += pad256(128);
  unsigned short* wt      = (unsigned short*)(ws + off); off += pad256((size_t)9 * 384 * 256 * 2);
  float*          bias_in = (float*)(ws + off);          off += pad256(384 * 4);
  unsigned short* wo2     = (unsigned short*)(ws + off); off += pad256(256 * 256 * 2);
  float*          bias_out= (float*)(ws + off);          off += pad256(256 * 4);
  float*          wkf     = (float*)(ws + off);          off += pad256(64 * 4 * 4);
  float*          bias_k  = (float*)(ws + off);          off += pad256(64 * 4);
  float*          wvf     = (float*)(ws + off);          off += pad256(128 * 4 * 4);
  float*          bias_v  = (float*)(ws + off);          off += pad256(128 * 4);
  unsigned short* xnp     = (unsigned short*)(ws + off); off += pad256((size_t)16 * 66 * 66 * 256 * 2);
  unsigned short* y       = (unsigned short*)(ws + off); off += pad256((size_t)16 * 4096 * 384 * 2);
  unsigned short* kk      = (unsigned short*)(ws + off); off += pad256((size_t)16 * 1024 * 64 * 2);
  unsigned short* vv      = (unsigned short*)(ws + off); off += pad256((size_t)16 * 128 * 1024 * 2);
  (void)ws_size; (void)out_size; (void)n_in; (void)in_sizes;

  hipMemsetAsync(stats, 0, 256, stream);
  hipMemsetAsync(xnp, 0, (size_t)16 * 66 * 66 * 256 * 2, stream);

  k_gn_stats<<<1024, 256, 0, stream>>>(x, stats);
  k_prep_wt<<<3456, 256, 0, stream>>>(w_in, bin_g, bin_v, wt);
  k_prep_misc<<<260, 256, 0, stream>>>(w_out, bo_g, bo_b, bo_m, bo_v,
                                       bin_g, bin_b, bin_m, bin_v,
                                       w_k, bk_g, bk_b, bk_m, bk_v,
                                       w_v, bv_g, bv_b, bv_m, bv_v,
                                       wo2, bias_in, bias_out, wkf, bias_k, wvf, bias_v);
  k_gn_norm<<<dim3(64, 4, 16), 256, 0, stream>>>(x, stats, gn_g, gn_b, xnp);
  k_conv3<<<dim3(32, 3, 16), 256, 0, stream>>>(xnp, wt, bias_in, y);
  k_kv<<<12288, 256, 0, stream>>>(y, wkf, bias_k, wvf, bias_v, kk, vv);
  k_attn<<<512, 256, 0, stream>>>(y, kk, vv);
  k_conv1<<<dim3(32, 2, 16), 256, 0, stream>>>(y, wo2, bias_out, out);
}